// Round 5
// baseline (419.435 us; speedup 1.0000x reference)
//
#include <hip/hip_runtime.h>

// Fused attention block (b=2, n=2048, dim=256, heads=8, inner=16384, d_head=2048)
// LOW-RANK: S_h = xn M_h xn^T (M_h = Wq_h^T Wk_h), Zt_h = N_h xn^T (N_h = Wo_h Wv_h).
// R15: barrier-minimal attn core. S-phase B-operands are wave-private -> loaded
// global->VGPR directly (compiler-tracked deps, no LDS, no barriers). Z: all 4
// subtiles (64KB) staged during S4-S7; PV runs barrier-free from full LDS tile.
// Pl: XOR-swizzled [64][128] (byte ^= (row&7)<<4), no pad; l_lds aliases dead Pl.
// LDS = 64K(Z) + 16K(Pl) = 81920 B exactly -> 2 blocks/CU. Barriers: 192 -> 32
// (2 per j-tile: post-exp with lgkm0+vmcnt0, end-of-PV). Epilogue: R14's plain
// per-head partial stores + hreduce (no global atomics).

typedef unsigned short u16;
typedef unsigned int u32;
typedef __bf16 bf16x8 __attribute__((ext_vector_type(8)));
typedef float f32x4 __attribute__((ext_vector_type(4)));

__device__ __forceinline__ u16 f2bf(float f) {
    u32 u = __builtin_bit_cast(u32, f);
    u += 0x7fffu + ((u >> 16) & 1u);   // RNE; inputs finite
    return (u16)(u >> 16);
}

#define GLDS16(G, L)                                                                  \
    __builtin_amdgcn_global_load_lds((const __attribute__((address_space(1))) u32*)(G), \
                                     (__attribute__((address_space(3))) u32*)(L), 16, 0, 0)

template <int N> __device__ __forceinline__ void vm_wait() {
    asm volatile("s_waitcnt vmcnt(%0)" :: "n"(N) : "memory");
}
__device__ __forceinline__ void lgk0() {
    asm volatile("s_waitcnt lgkmcnt(0)" ::: "memory");
}
__device__ __forceinline__ void bar() {
    __builtin_amdgcn_s_barrier();
    __builtin_amdgcn_sched_barrier(0);
}

// ---------------------------------------------------------------------------
// B^T GEMM: C[m,n] (+)= sum_k A[m,k]*B[n,k].  blockIdx.z = (kc*NB+zb)*H + zh.
// Triple-buffered LDS, issue distance 2, counted vmcnt, one barrier per K-step.
// ---------------------------------------------------------------------------
template <typename OutT, bool ATOMIC>
__global__ void __launch_bounds__(256, 3) gemm_bt(
    const u16* __restrict__ A, const u16* __restrict__ B, OutT* __restrict__ C,
    int K, int lda, int ldb, int ldc,
    long sAh, long sAb, long sBh, long sBb, long sCh, long sCb,
    int H, int NB, long ksA, long ksB)
{
    __shared__ u16 ldsA[3][128 * 32];
    __shared__ u16 ldsB[3][128 * 32];

    const int z = blockIdx.z;
    const int zh = z % H;
    const int zq = z / H;
    const int zb = zq % NB;
    const int kc = zq / NB;
    A += (size_t)zh * sAh + (size_t)zb * sAb + (size_t)kc * ksA;
    B += (size_t)zh * sBh + (size_t)zb * sBb + (size_t)kc * ksB;
    C += (size_t)zh * sCh + (size_t)zb * sCb;

    const int bm = blockIdx.y * 128;
    const int bn = blockIdx.x * 128;
    const int t = threadIdx.x;
    const int w = t >> 6, l = t & 63;
    const int wm = w >> 1, wn = w & 1;
    const int lr = l & 15, lk = l >> 4;
    const int sw = lk ^ ((lr >> 1) & 3);

    const int m0 = t >> 2, s0 = t & 3;
    const int c0 = s0 ^ ((m0 >> 1) & 3);
    const int m1 = 64 + m0;
    const int c1 = s0 ^ ((m1 >> 1) & 3);
    const int o0 = (t & ~63) * 8;
    const int o1 = (256 + (t & ~63)) * 8;

    const u16* gA0 = A + (size_t)(bm + m0) * lda + c0 * 8;
    const u16* gA1 = A + (size_t)(bm + m1) * lda + c1 * 8;
    const u16* gB0 = B + (size_t)(bn + m0) * ldb + c0 * 8;
    const u16* gB1 = B + (size_t)(bn + m1) * ldb + c1 * 8;

    f32x4 acc[4][4];
#pragma unroll
    for (int i = 0; i < 4; ++i)
#pragma unroll
        for (int j = 0; j < 4; ++j)
            acc[i][j] = f32x4{0.f, 0.f, 0.f, 0.f};

    const int nk = K >> 5;

    // prologue: stage k-tiles 0,1 into buffers 0,1 (queue: [k0(4), k1(4)])
    GLDS16(gA0, &ldsA[0][o0]); GLDS16(gA1, &ldsA[0][o1]);
    GLDS16(gB0, &ldsB[0][o0]); GLDS16(gB1, &ldsB[0][o1]);
    gA0 += 32; gA1 += 32; gB0 += 32; gB1 += 32;
    GLDS16(gA0, &ldsA[1][o0]); GLDS16(gA1, &ldsA[1][o1]);
    GLDS16(gB0, &ldsB[1][o0]); GLDS16(gB1, &ldsB[1][o1]);
    gA0 += 32; gA1 += 32; gB0 += 32; gB1 += 32;

    int cur = 0, wsl = 2;
    for (int kt = 0; kt < nk - 1; ++kt) {
        // queue before wait: [kt(4), kt+1(4)] -> retire kt, keep kt+1 in flight
        vm_wait<4>(); bar();
        if (kt + 2 < nk) {             // writer slot == (kt-1)'s reader slot: safe post-barrier
            GLDS16(gA0, &ldsA[wsl][o0]); GLDS16(gA1, &ldsA[wsl][o1]);
            GLDS16(gB0, &ldsB[wsl][o0]); GLDS16(gB1, &ldsB[wsl][o1]);
            gA0 += 32; gA1 += 32; gB0 += 32; gB1 += 32;
        }
        bf16x8 av[4], bv[4];
#pragma unroll
        for (int i = 0; i < 4; ++i) {
            av[i] = *(const bf16x8*)&ldsA[cur][(wm * 64 + i * 16 + lr) * 32 + sw * 8];
            bv[i] = *(const bf16x8*)&ldsB[cur][(wn * 64 + i * 16 + lr) * 32 + sw * 8];
        }
        __builtin_amdgcn_s_setprio(1);
#pragma unroll
        for (int i = 0; i < 4; ++i)
#pragma unroll
            for (int j = 0; j < 4; ++j)
                acc[i][j] = __builtin_amdgcn_mfma_f32_16x16x32_bf16(av[i], bv[j], acc[i][j], 0, 0, 0);
        __builtin_amdgcn_s_setprio(0);
        cur = (cur == 2) ? 0 : cur + 1;
        wsl = (wsl == 2) ? 0 : wsl + 1;
    }
    // peeled last tile: only [nk-1] outstanding
    vm_wait<0>(); bar();
    {
        bf16x8 av[4], bv[4];
#pragma unroll
        for (int i = 0; i < 4; ++i) {
            av[i] = *(const bf16x8*)&ldsA[cur][(wm * 64 + i * 16 + lr) * 32 + sw * 8];
            bv[i] = *(const bf16x8*)&ldsB[cur][(wn * 64 + i * 16 + lr) * 32 + sw * 8];
        }
        __builtin_amdgcn_s_setprio(1);
#pragma unroll
        for (int i = 0; i < 4; ++i)
#pragma unroll
            for (int j = 0; j < 4; ++j)
                acc[i][j] = __builtin_amdgcn_mfma_f32_16x16x32_bf16(av[i], bv[j], acc[i][j], 0, 0, 0);
        __builtin_amdgcn_s_setprio(0);
    }

    // C/D layout: col = lane&15, row = (lane>>4)*4 + reg
#pragma unroll
    for (int i = 0; i < 4; ++i) {
        const int row0 = bm + wm * 64 + i * 16 + lk * 4;
#pragma unroll
        for (int j = 0; j < 4; ++j) {
            const int col = bn + wn * 64 + j * 16 + lr;
#pragma unroll
            for (int r = 0; r < 4; ++r) {
                const size_t idx = (size_t)(row0 + r) * ldc + col;
                const float v = acc[i][j][r];
                if constexpr (ATOMIC) {
                    atomicAdd(&C[idx], v);
                } else if constexpr (sizeof(OutT) == 2) {
                    C[idx] = (OutT)f2bf(v);
                } else {
                    C[idx] = (OutT)v;
                }
            }
        }
    }
}

// ---------------------------------------------------------------------------
// Flash-fused attention core.  512 blocks, 256 thr, 2 blocks/CU.
// Y  : [4096][2048] (SCALE folded) -> REGISTERS (yr, via LDS prologue)
// xn : B-operand frags loaded global->VGPR per wave (no LDS, no barriers)
// Zt : all 4 K-subtiles staged to ldsZ[4] during S4-S7; PV barrier-free
// Pl : [64][128] u16, XOR-swizzled (chunk ^= (row&7)); l_lds aliases Pl after loop
// opart: [8][4096][256] fp32 per-head partials (plain stores)
// ---------------------------------------------------------------------------
__global__ void __launch_bounds__(256, 2) attn_fused(
    const u16* __restrict__ Y, const u16* __restrict__ xn,
    const u16* __restrict__ Zt, float* __restrict__ opart)
{
    __shared__ u16 ldsZ[4][8192];      // 64 KB (prologue: Y tile in ldsZ[0..1])
    __shared__ u16 Pl[8192];           // 16 KB, swizzled; total 81920 B exactly

    // bijective XCD swizzle: w = x + 32*y; xcd = w&7 gets hb in {2*xcd, 2*xcd+1}
    const int wgid = blockIdx.x + 32 * blockIdx.y;
    const int xcd = wgid & 7;
    const int p = wgid >> 3;           // 0..63
    const int hb = 2 * xcd + (p & 1);
    const int i0 = (p >> 1) * 64;
    const int h = hb >> 1, b = hb & 1;

    const int t = threadIdx.x;
    const int w = t >> 6, l = t & 63;
    const int wm = w >> 1, wn = w & 1;
    const int lr = l & 15, lk = l >> 4;
    const int sw = lk ^ ((lr >> 1) & 3);

    const u16* Yb = Y + (size_t)(b * 2048 + i0) * 2048 + h * 256;
    const u16* xb = xn + (size_t)b * 2048 * 256;
    const u16* Zb = Zt + (size_t)b * 4194304 + (size_t)h * 524288;

    // Z staging roles (4 chunks/thread per 16KB subtile)
    const u16 *gZ0, *gZ1, *gZ2, *gZ3;
    const int oZ0 = (t & ~63) * 8;
    const int oZ1 = (256 + (t & ~63)) * 8;
    const int oZ2 = (512 + (t & ~63)) * 8;
    const int oZ3 = (768 + (t & ~63)) * 8;
    {
        const int q0 = t, q1 = 256 + t, q2 = 512 + t, q3 = 768 + t;
        const int mz0 = q0 >> 2, mz1 = q1 >> 2, mz2 = q2 >> 2, mz3 = q3 >> 2;
        const int cz0 = (q0 & 3) ^ ((mz0 >> 1) & 3);
        const int cz1 = (q1 & 3) ^ ((mz1 >> 1) & 3);
        const int cz2 = (q2 & 3) ^ ((mz2 >> 1) & 3);
        const int cz3 = (q3 & 3) ^ ((mz3 >> 1) & 3);
        gZ0 = Zb + (size_t)mz0 * 2048 + cz0 * 8;
        gZ1 = Zb + (size_t)mz1 * 2048 + cz1 * 8;
        gZ2 = Zb + (size_t)mz2 * 2048 + cz2 * 8;
        gZ3 = Zb + (size_t)mz3 * 2048 + cz3 * 8;
    }

    // ---- prologue: stage Y i-tile (64x256 = 32KB) into ldsZ[0..1] ----
    u16* ldsY = &ldsZ[0][0];
#pragma unroll
    for (int pp = 0; pp < 8; ++pp) {
        const int q = pp * 256 + t;
        const int kt = q >> 8, qq = q & 255;
        const int m = qq >> 2, s = qq & 3;
        const int c = s ^ ((m >> 1) & 3);
        GLDS16(Yb + (size_t)m * 2048 + kt * 32 + c * 8,
               &ldsY[(pp * 256 + (t & ~63)) * 8]);
    }
    vm_wait<0>();
    bar();

    // Y fragments -> registers (jt-invariant): 16x bf16x8 = 64 VGPR
    bf16x8 yr[8][2];
#pragma unroll
    for (int kt = 0; kt < 8; ++kt)
#pragma unroll
        for (int i = 0; i < 2; ++i)
            yr[kt][i] = *(const bf16x8*)&ldsY[kt * 2048 + (wm * 32 + i * 16 + lr) * 32 + sw * 8];
    lgk0();
    bar();                             // no wave may clobber ldsY (Z staging) early

    f32x4 acc_o[2][8];
#pragma unroll
    for (int i = 0; i < 2; ++i)
#pragma unroll
        for (int j = 0; j < 8; ++j)
            acc_o[i][j] = f32x4{0.f, 0.f, 0.f, 0.f};
    float lsum[8];
#pragma unroll
    for (int i = 0; i < 8; ++i) lsum[i] = 0.f;

    // B-frag loader: frag j of K-step kk from j-tile base (wave-private, coalesced
    // per 64B segment, L2-hot). Data identical to the old LDS-staged bv.
#define BFRAG(SRC, KK, J) \
    (*(const bf16x8*)((SRC) + (size_t)(wn * 64 + (J) * 16 + lr) * 256 + (KK) * 32 + lk * 8))

    // pre-issue B frags for kt=0,1 of jt=0
    bf16x8 bcur[4], bnxt[4];
#pragma unroll
    for (int j = 0; j < 4; ++j) bcur[j] = BFRAG(xb, 0, j);
#pragma unroll
    for (int j = 0; j < 4; ++j) bnxt[j] = BFRAG(xb, 1, j);

    for (int jt = 0; jt < 16; ++jt) {
        const int j0 = jt * 128;
        const u16* xbj = xb + (size_t)j0 * 256;
        const u16* xbn = xb + (size_t)(((jt + 1) & 15) * 128) * 256;  // wrap: dummy

        f32x4 acc_s[2][4];
#pragma unroll
        for (int i = 0; i < 2; ++i)
#pragma unroll
            for (int j = 0; j < 4; ++j)
                acc_s[i][j] = f32x4{0.f, 0.f, 0.f, 0.f};

        // ---- S phase: 8 K-steps, NO barriers (B in regs, Y in regs) ----
#pragma unroll
        for (int kt = 0; kt < 8; ++kt) {
            bf16x8 bnx2[4];
            const u16* src = (kt < 6) ? xbj : xbn;
            const int kk = (kt < 6) ? (kt + 2) : (kt - 6);
#pragma unroll
            for (int j = 0; j < 4; ++j) bnx2[j] = BFRAG(src, kk, j);
            if (kt >= 4) {             // stage Z subtile kt-4 (16KB) into ldsZ[kt-4]
                const int zi = kt - 4;
                GLDS16(gZ0 + j0 + zi * 32, &ldsZ[zi][oZ0]);
                GLDS16(gZ1 + j0 + zi * 32, &ldsZ[zi][oZ1]);
                GLDS16(gZ2 + j0 + zi * 32, &ldsZ[zi][oZ2]);
                GLDS16(gZ3 + j0 + zi * 32, &ldsZ[zi][oZ3]);
            }
            __builtin_amdgcn_s_setprio(1);
#pragma unroll
            for (int j = 0; j < 4; ++j) {
                acc_s[0][j] = __builtin_amdgcn_mfma_f32_16x16x32_bf16(yr[kt][0], bcur[j], acc_s[0][j], 0, 0, 0);
                acc_s[1][j] = __builtin_amdgcn_mfma_f32_16x16x32_bf16(yr[kt][1], bcur[j], acc_s[1][j], 0, 0, 0);
            }
            __builtin_amdgcn_s_setprio(0);
#pragma unroll
            for (int j = 0; j < 4; ++j) { bcur[j] = bnxt[j]; bnxt[j] = bnx2[j]; }
        }

        // ---- exp + l partials + P -> swizzled Pl[row][col^((row&7)*8)] ----
#pragma unroll
        for (int i = 0; i < 2; ++i)
#pragma unroll
            for (int j = 0; j < 4; ++j)
#pragma unroll
                for (int r = 0; r < 4; ++r) {
                    const int row = wm * 32 + i * 16 + lk * 4 + r;
                    const int col = wn * 64 + j * 16 + lr;
                    const float e = __expf(acc_s[i][j][r]);
                    lsum[i * 4 + r] += e;
                    Pl[row * 128 + (col ^ ((row & 7) * 8))] = f2bf(e);
                }
        lgk0();                        // Pl ds_writes done
        vm_wait<0>();                  // all Z GLDS writes landed (drains B prefetch too)
        bar();                         // Pl + Z visible to all waves

        // ---- PV phase: 4 K-steps, NO barriers (Z fully staged) ----
#pragma unroll
        for (int kt = 0; kt < 4; ++kt) {
            const int swz = (lr & 7) * 8;
            bf16x8 av0 = *(const bf16x8*)&Pl[(wm * 32 + lr) * 128 + ((kt * 32 + lk * 8) ^ swz)];
            bf16x8 av1 = *(const bf16x8*)&Pl[(wm * 32 + 16 + lr) * 128 + ((kt * 32 + lk * 8) ^ swz)];
            __builtin_amdgcn_s_setprio(1);
#pragma unroll
            for (int jf = 0; jf < 8; ++jf) {
                const bf16x8 bz = *(const bf16x8*)&ldsZ[kt][(wn * 128 + jf * 16 + lr) * 32 + sw * 8];
                acc_o[0][jf] = __builtin_amdgcn_mfma_f32_16x16x32_bf16(av0, bz, acc_o[0][jf], 0, 0, 0);
                acc_o[1][jf] = __builtin_amdgcn_mfma_f32_16x16x32_bf16(av1, bz, acc_o[1][jf], 0, 0, 0);
            }
            __builtin_amdgcn_s_setprio(0);
            __builtin_amdgcn_sched_barrier(0);
        }
        bar();                         // close j-tile: Pl/Z rewrite safe after this
    }

    // ---- finalize l: butterfly over lr lanes, cross-wave LDS atomic ----
    float* l_lds = (float*)Pl;         // Pl dead after final PV
    if (t < 64) l_lds[t] = 0.f;
    __syncthreads();
#pragma unroll
    for (int i = 0; i < 2; ++i)
#pragma unroll
        for (int r = 0; r < 4; ++r) {
            float s = lsum[i * 4 + r];
            s += __shfl_xor(s, 1, 64);
            s += __shfl_xor(s, 2, 64);
            s += __shfl_xor(s, 4, 64);
            s += __shfl_xor(s, 8, 64);
            if (lr == 0) atomicAdd(&l_lds[wm * 32 + i * 16 + lk * 4 + r], s);
        }
    __syncthreads();

    // ---- scale by 1/l, plain-store per-head partial (NO global atomics) ----
    float* oh = opart + (size_t)h * 1048576;   // 4096*256 floats per head
#pragma unroll
    for (int i = 0; i < 2; ++i)
#pragma unroll
        for (int r = 0; r < 4; ++r) {
            const int row = wm * 32 + i * 16 + lk * 4 + r;
            const float rl = 1.0f / l_lds[row];
            float* orow = oh + (size_t)(b * 2048 + i0 + row) * 256 + wn * 128;
#pragma unroll
            for (int jf = 0; jf < 8; ++jf)
                orow[jf * 16 + lr] = acc_o[i][jf][r] * rl;
        }
}

// ---------------------------------------------------------------------------
// Head reduction: out[i] = sum_h opart[h][i], i over 4096*256 fp32.
// ---------------------------------------------------------------------------
__global__ void __launch_bounds__(256) hreduce_kernel(const float* __restrict__ opart,
                                                      float* __restrict__ out)
{
    const size_t i = (size_t)blockIdx.x * 256 + threadIdx.x;   // float4 index
    float4 s = ((const float4*)opart)[i];
#pragma unroll
    for (int h = 1; h < 8; ++h) {
        const float4 v = ((const float4*)(opart + (size_t)h * 1048576))[i];
        s.x += v.x; s.y += v.y; s.z += v.z; s.w += v.w;
    }
    ((float4*)out)[i] = s;
}

// ---------------------------------------------------------------------------
// Transposed cast for Wq/Wk/Wv in one dispatch: z = wsel*8 + h.
// src fp32 [8][2048][256] -> dst bf16 [8][256][2048] (contiguous 3 weights).
// ---------------------------------------------------------------------------
__global__ void __launch_bounds__(256) tcast3_kernel(const float* __restrict__ Wq,
                                                     const float* __restrict__ Wk,
                                                     const float* __restrict__ Wv,
                                                     u16* __restrict__ dst)
{
    __shared__ u16 tile[64][66];
    const int z = blockIdx.z;
    const int wsel = z >> 3, h = z & 7;
    const float* src = (wsel == 0) ? Wq : (wsel == 1) ? Wk : Wv;
    const float scale = (wsel == 0) ? 0.125f : 1.0f;
    u16* d = dst + (size_t)wsel * 4194304;
    const int d0 = blockIdx.x * 64;
    const int a0 = blockIdx.y * 64;
    const int t = threadIdx.x;
    const int c = t & 63, r0 = t >> 6;
#pragma unroll
    for (int rr = 0; rr < 16; ++rr) {
        const int r = r0 + rr * 4;
        tile[r][c] = f2bf(src[((size_t)h * 2048 + d0 + r) * 256 + a0 + c] * scale);
    }
    __syncthreads();
#pragma unroll
    for (int rr = 0; rr < 16; ++rr) {
        const int r = r0 + rr * 4;
        d[((size_t)h * 256 + a0 + r) * 2048 + d0 + c] = tile[c][r];
    }
}

__global__ void __launch_bounds__(64) ln_kernel(const float* __restrict__ x,
                                                const float* __restrict__ g,
                                                u16* __restrict__ xn)
{
    const size_t row = blockIdx.x;
    const int l = threadIdx.x;
    const float4 v = ((const float4*)(x + row * 256))[l];
    float s = v.x + v.y + v.z + v.w;
    float q = v.x * v.x + v.y * v.y + v.z * v.z + v.w * v.w;
#pragma unroll
    for (int o = 32; o > 0; o >>= 1) {
        s += __shfl_xor(s, o, 64);
        q += __shfl_xor(q, o, 64);
    }
    const float mu = s * (1.0f / 256.0f);
    const float var = q * (1.0f / 256.0f) - mu * mu;
    const float rs = rsqrtf(var + 1e-5f);
    const float4 gg = ((const float4*)g)[l];
    ushort4 o4;
    o4.x = f2bf((v.x - mu) * rs * (gg.x + 1.0f));
    o4.y = f2bf((v.y - mu) * rs * (gg.y + 1.0f));
    o4.z = f2bf((v.z - mu) * rs * (gg.z + 1.0f));
    o4.w = f2bf((v.w - mu) * rs * (gg.w + 1.0f));
    ((ushort4*)(xn + row * 256))[l] = o4;
}

__global__ void __launch_bounds__(256) cast_bf16_kernel(const float* __restrict__ src,
                                                        u16* __restrict__ dst, float scale)
{
    const size_t i = (size_t)blockIdx.x * 256 + threadIdx.x;
    const float4 v = ((const float4*)src)[i];
    ushort4 o4;
    o4.x = f2bf(v.x * scale);
    o4.y = f2bf(v.y * scale);
    o4.z = f2bf(v.z * scale);
    o4.w = f2bf(v.w * scale);
    ((ushort4*)dst)[i] = o4;
}

extern "C" void kernel_launch(void* const* d_in, const int* in_sizes, int n_in,
                              void* d_out, int out_size, void* d_ws, size_t ws_size,
                              hipStream_t stream)
{
    (void)in_sizes; (void)n_in; (void)ws_size; (void)out_size;
    const float* x     = (const float*)d_in[0];
    const float* gamma = (const float*)d_in[1];
    const float* Wq    = (const float*)d_in[2];
    const float* Wk    = (const float*)d_in[3];
    const float* Wv    = (const float*)d_in[4];
    const float* Wo    = (const float*)d_in[5];
    float* out = (float*)d_out;

    char* ws = (char*)d_ws;
    const size_t MB = 1048576;
    u16* wqt   = (u16*)(ws);             // [3][8][256][2048] bf16 (SCALE folded in Wq)
    u16* wkt   = (u16*)(ws + 8 * MB);
    u16* wvt   = (u16*)(ws + 16 * MB);
    u16* wo    = (u16*)(ws + 24 * MB);   // [256][16384] bf16
    u16* xn    = (u16*)(ws + 32 * MB);   // [4096][256] bf16
    u16* Mt    = (u16*)(ws + 34 * MB);   // [8*256][256] bf16 (Mt_h = M_h^T)
    u16* Nb    = (u16*)(ws + 35 * MB);   // [8*256][256] bf16 (contiguous after Mt)
    float* MtF = (float*)(ws + 36 * MB); // fp32 split-K accum: Mt (2 MB) + Nb (2 MB)
    float* NbF = (float*)(ws + 38 * MB);
    u16* Y     = (u16*)(ws + 44 * MB);   // [4096][2048] bf16
    u16* Zt    = (u16*)(ws + 60 * MB);   // [2][2048][2048] bf16
    float* opart = (float*)(ws);         // [8][4096][256] fp32 (stride 1048576
                                         // floats/head, 32 MB) -- reuses dead
                                         // weight-staging region 0..32MB.

    hipMemsetAsync(MtF, 0, 4 * MB, stream);

    tcast3_kernel<<<dim3(32, 4, 24), 256, 0, stream>>>(Wq, Wk, Wv, wqt);
    cast_bf16_kernel<<<4096, 256, 0, stream>>>(Wo, wo, 1.0f);
    ln_kernel<<<4096, 64, 0, stream>>>(x, gamma, xn);

    // Mt_h[a,c] = sum_e wkt_h[a,e]*wqt_h[c,e] : split-K x4 (K-chunk 512), fp32 atomic
    gemm_bt<float, true><<<dim3(2, 2, 32), 256, 0, stream>>>(
        wkt, wqt, MtF, 512, 2048, 2048, 256,
        524288L, 0, 524288L, 0, 65536L, 0, 8, 1, 512L, 512L);

    // N_h[d',a] = sum_e Wo[d',h*2048+e]*wvt_h[a,e] : split-K x4, fp32 atomic
    gemm_bt<float, true><<<dim3(2, 2, 32), 256, 0, stream>>>(
        wo, wvt, NbF, 512, 16384, 2048, 256,
        2048L, 0, 524288L, 0, 65536L, 0, 8, 1, 512L, 512L);

    // cast MtF+NbF (4 MB contiguous) -> Mt+Nb (2 MB contiguous)
    cast_bf16_kernel<<<1024, 256, 0, stream>>>(MtF, Mt, 1.0f);

    // Y[t, h*256+a] = sum_c xn[t,c] * Mt[h*256+a, c]
    gemm_bt<u16, false><<<dim3(16, 32, 1), 256, 0, stream>>>(
        xn, Mt, Y, 256, 256, 256, 2048,
        0, 0, 0, 0, 0, 0, 1, 1, 0, 0);

    // Zt[b][h*256+d', j] = sum_a Nb[h*256+d', a] * xn[b*2048+j, a]
    gemm_bt<u16, false><<<dim3(16, 16, 2), 256, 0, stream>>>(
        Nb, xn, Zt, 256, 256, 256, 2048,
        0, 0, 0, 524288L, 0, 4194304L, 1, 2, 0, 0);

    // fused S -> softmax -> PV -> per-head partial stores
    attn_fused<<<dim3(32, 16), 256, 0, stream>>>(Y, xn, Zt, opart);

    // head-sum reduction: out = sum_h opart[h]
    hreduce_kernel<<<1024, 256, 0, stream>>>(opart, out);
}

// Round 6
// 253.836 us; speedup vs baseline: 1.6524x; 1.6524x over previous
//
#include <hip/hip_runtime.h>

// Fused attention block (b=2, n=2048, dim=256, heads=8, inner=16384, d_head=2048)
// LOW-RANK: S_h = xn M_h xn^T (M_h = Wq_h^T Wk_h), Zt_h = N_h xn^T (N_h = Wo_h Wv_h).
// R16: attn_fused reverted to R14 verbatim (R15's reg-pipeline spilled: FETCH 24->142MB
// scratch traffic). This round fuses the 11-dispatch prologue chain to 6:
//   prep_kernel  = tcast3 + cast_wo + ln + zero(MtF)      [9216 blocks, 1 dispatch]
//   gemm_w       = both weight GEMMs (split-K x4, atomics) [dim3(2,2,64)]
//   cast         = MtF/NbF -> Mt/Nb bf16
//   gemm_yz      = Y-GEMM (2 halves) + Zt-GEMM (2 batches) [dim3(16,16,4)]
//   attn_fused   = R14 (counted vmcnt, 12 steps/jt, plain per-head stores)
//   hreduce      = head sum
// gemm body hoisted to __device__ gemm_core (single call site per kernel -> one
// LDS alloc). No memsets (prep zeroes MtF; hreduce writes out fully).

typedef unsigned short u16;
typedef unsigned int u32;
typedef __bf16 bf16x8 __attribute__((ext_vector_type(8)));
typedef float f32x4 __attribute__((ext_vector_type(4)));

__device__ __forceinline__ u16 f2bf(float f) {
    u32 u = __builtin_bit_cast(u32, f);
    u += 0x7fffu + ((u >> 16) & 1u);   // RNE; inputs finite
    return (u16)(u >> 16);
}

#define GLDS16(G, L)                                                                  \
    __builtin_amdgcn_global_load_lds((const __attribute__((address_space(1))) u32*)(G), \
                                     (__attribute__((address_space(3))) u32*)(L), 16, 0, 0)

template <int N> __device__ __forceinline__ void vm_wait() {
    asm volatile("s_waitcnt vmcnt(%0)" :: "n"(N) : "memory");
}
__device__ __forceinline__ void lgk0() {
    asm volatile("s_waitcnt lgkmcnt(0)" ::: "memory");
}
__device__ __forceinline__ void bar() {
    __builtin_amdgcn_s_barrier();
    __builtin_amdgcn_sched_barrier(0);
}

// ---------------------------------------------------------------------------
// Shared GEMM core: C[m,n] (+)= sum_k A[m,k]*B[n,k] for one 128x128 tile at
// (blockIdx.y*128, blockIdx.x*128). Triple-buffered LDS, issue distance 2,
// counted vmcnt, one barrier per K-step. A/B/C pre-offset by caller.
// ---------------------------------------------------------------------------
template <typename OutT, bool ATOMIC>
__device__ __forceinline__ void gemm_core(
    const u16* __restrict__ A, const u16* __restrict__ B, OutT* __restrict__ C,
    int K, int lda, int ldb, int ldc)
{
    __shared__ u16 ldsA[3][128 * 32];
    __shared__ u16 ldsB[3][128 * 32];

    const int bm = blockIdx.y * 128;
    const int bn = blockIdx.x * 128;
    const int t = threadIdx.x;
    const int w = t >> 6, l = t & 63;
    const int wm = w >> 1, wn = w & 1;
    const int lr = l & 15, lk = l >> 4;
    const int sw = lk ^ ((lr >> 1) & 3);

    const int m0 = t >> 2, s0 = t & 3;
    const int c0 = s0 ^ ((m0 >> 1) & 3);
    const int m1 = 64 + m0;
    const int c1 = s0 ^ ((m1 >> 1) & 3);
    const int o0 = (t & ~63) * 8;
    const int o1 = (256 + (t & ~63)) * 8;

    const u16* gA0 = A + (size_t)(bm + m0) * lda + c0 * 8;
    const u16* gA1 = A + (size_t)(bm + m1) * lda + c1 * 8;
    const u16* gB0 = B + (size_t)(bn + m0) * ldb + c0 * 8;
    const u16* gB1 = B + (size_t)(bn + m1) * ldb + c1 * 8;

    f32x4 acc[4][4];
#pragma unroll
    for (int i = 0; i < 4; ++i)
#pragma unroll
        for (int j = 0; j < 4; ++j)
            acc[i][j] = f32x4{0.f, 0.f, 0.f, 0.f};

    const int nk = K >> 5;

    // prologue: stage k-tiles 0,1 into buffers 0,1 (queue: [k0(4), k1(4)])
    GLDS16(gA0, &ldsA[0][o0]); GLDS16(gA1, &ldsA[0][o1]);
    GLDS16(gB0, &ldsB[0][o0]); GLDS16(gB1, &ldsB[0][o1]);
    gA0 += 32; gA1 += 32; gB0 += 32; gB1 += 32;
    GLDS16(gA0, &ldsA[1][o0]); GLDS16(gA1, &ldsA[1][o1]);
    GLDS16(gB0, &ldsB[1][o0]); GLDS16(gB1, &ldsB[1][o1]);
    gA0 += 32; gA1 += 32; gB0 += 32; gB1 += 32;

    int cur = 0, wsl = 2;
    for (int kt = 0; kt < nk - 1; ++kt) {
        // queue before wait: [kt(4), kt+1(4)] -> retire kt, keep kt+1 in flight
        vm_wait<4>(); bar();
        if (kt + 2 < nk) {             // writer slot == (kt-1)'s reader slot: safe post-barrier
            GLDS16(gA0, &ldsA[wsl][o0]); GLDS16(gA1, &ldsA[wsl][o1]);
            GLDS16(gB0, &ldsB[wsl][o0]); GLDS16(gB1, &ldsB[wsl][o1]);
            gA0 += 32; gA1 += 32; gB0 += 32; gB1 += 32;
        }
        bf16x8 av[4], bv[4];
#pragma unroll
        for (int i = 0; i < 4; ++i) {
            av[i] = *(const bf16x8*)&ldsA[cur][(wm * 64 + i * 16 + lr) * 32 + sw * 8];
            bv[i] = *(const bf16x8*)&ldsB[cur][(wn * 64 + i * 16 + lr) * 32 + sw * 8];
        }
        __builtin_amdgcn_s_setprio(1);
#pragma unroll
        for (int i = 0; i < 4; ++i)
#pragma unroll
            for (int j = 0; j < 4; ++j)
                acc[i][j] = __builtin_amdgcn_mfma_f32_16x16x32_bf16(av[i], bv[j], acc[i][j], 0, 0, 0);
        __builtin_amdgcn_s_setprio(0);
        cur = (cur == 2) ? 0 : cur + 1;
        wsl = (wsl == 2) ? 0 : wsl + 1;
    }
    // peeled last tile: only [nk-1] outstanding
    vm_wait<0>(); bar();
    {
        bf16x8 av[4], bv[4];
#pragma unroll
        for (int i = 0; i < 4; ++i) {
            av[i] = *(const bf16x8*)&ldsA[cur][(wm * 64 + i * 16 + lr) * 32 + sw * 8];
            bv[i] = *(const bf16x8*)&ldsB[cur][(wn * 64 + i * 16 + lr) * 32 + sw * 8];
        }
        __builtin_amdgcn_s_setprio(1);
#pragma unroll
        for (int i = 0; i < 4; ++i)
#pragma unroll
            for (int j = 0; j < 4; ++j)
                acc[i][j] = __builtin_amdgcn_mfma_f32_16x16x32_bf16(av[i], bv[j], acc[i][j], 0, 0, 0);
        __builtin_amdgcn_s_setprio(0);
    }

    // C/D layout: col = lane&15, row = (lane>>4)*4 + reg
#pragma unroll
    for (int i = 0; i < 4; ++i) {
        const int row0 = bm + wm * 64 + i * 16 + lk * 4;
#pragma unroll
        for (int j = 0; j < 4; ++j) {
            const int col = bn + wn * 64 + j * 16 + lr;
#pragma unroll
            for (int r = 0; r < 4; ++r) {
                const size_t idx = (size_t)(row0 + r) * ldc + col;
                const float v = acc[i][j][r];
                if constexpr (ATOMIC) {
                    atomicAdd(&C[idx], v);
                } else if constexpr (sizeof(OutT) == 2) {
                    C[idx] = (OutT)f2bf(v);
                } else {
                    C[idx] = (OutT)v;
                }
            }
        }
    }
}

// Both weight GEMMs in one dispatch. grid dim3(2,2,64).
// z: zh = z&7 (head), q = z>>3, which = q&1 (0: Mt, 1: Nb), kc = q>>1 (split-K x4).
__global__ void __launch_bounds__(256, 3) gemm_w(
    const u16* __restrict__ wkt, const u16* __restrict__ wqt,
    const u16* __restrict__ wo, const u16* __restrict__ wvt,
    float* __restrict__ MtF)
{
    const int z = blockIdx.z;
    const int zh = z & 7;
    const int q = z >> 3;
    const int which = q & 1;
    const int kc = q >> 1;
    const u16* A; const u16* B; float* C; int lda;
    if (which == 0) {
        A = wkt + (size_t)zh * 524288 + kc * 512; lda = 2048;
        B = wqt + (size_t)zh * 524288 + kc * 512;
        C = MtF + (size_t)zh * 65536;
    } else {
        A = wo + (size_t)zh * 2048 + kc * 512;    lda = 16384;
        B = wvt + (size_t)zh * 524288 + kc * 512;
        C = MtF + 524288 + (size_t)zh * 65536;
    }
    gemm_core<float, true>(A, B, C, 512, lda, 2048, 256);
}

// Y-GEMM (2 row-halves) + Zt-GEMM (2 batches) in one dispatch. grid dim3(16,16,4).
__global__ void __launch_bounds__(256, 3) gemm_yz(
    const u16* __restrict__ xn, const u16* __restrict__ Mt,
    const u16* __restrict__ Nb, u16* __restrict__ Y, u16* __restrict__ Zt)
{
    const int z = blockIdx.z;
    const u16* A; const u16* B; u16* C;
    if (z < 2) {            // Y[t, h*256+a] = sum_c xn[t,c] * Mt[h*256+a, c]
        A = xn + (size_t)z * 524288;           // rows z*2048.., lda=256
        B = Mt;
        C = Y + (size_t)z * 4194304;           // 2048 rows x 2048 cols
    } else {                // Zt[b][h*256+d', j] = sum_a Nb[h*256+d',a]*xn[b*2048+j,a]
        const int b = z - 2;
        A = Nb;
        B = xn + (size_t)b * 524288;
        C = Zt + (size_t)b * 4194304;
    }
    gemm_core<u16, false>(A, B, C, 256, 256, 256, 2048);
}

// ---------------------------------------------------------------------------
// Fused prologue: tcast3 (blocks 0..3071) + cast_wo (3072..7167) +
// ln (7168..8191, 4 rows/block) + zero MtF (8192..9215).
// ---------------------------------------------------------------------------
__global__ void __launch_bounds__(256) prep_kernel(
    const float* __restrict__ x, const float* __restrict__ g,
    const float* __restrict__ Wq, const float* __restrict__ Wk,
    const float* __restrict__ Wv, const float* __restrict__ Wo,
    u16* __restrict__ wqkv, u16* __restrict__ wo_b,
    u16* __restrict__ xn, float* __restrict__ MtF)
{
    __shared__ u16 tile[64][66];
    const int bid = blockIdx.x;
    const int t = threadIdx.x;
    if (bid < 3072) {
        // transposed cast: src fp32 [8][2048][256] -> dst bf16 [8][256][2048]
        const int bx = bid & 31, by = (bid >> 5) & 3, z = bid >> 7;
        const int wsel = z >> 3, h = z & 7;
        const float* src = (wsel == 0) ? Wq : (wsel == 1) ? Wk : Wv;
        const float scale = (wsel == 0) ? 0.125f : 1.0f;
        u16* d = wqkv + (size_t)wsel * 4194304;
        const int d0 = bx * 64;
        const int a0 = by * 64;
        const int c = t & 63, r0 = t >> 6;
#pragma unroll
        for (int rr = 0; rr < 16; ++rr) {
            const int r = r0 + rr * 4;
            tile[r][c] = f2bf(src[((size_t)h * 2048 + d0 + r) * 256 + a0 + c] * scale);
        }
        __syncthreads();
#pragma unroll
        for (int rr = 0; rr < 16; ++rr) {
            const int r = r0 + rr * 4;
            d[((size_t)h * 256 + a0 + r) * 2048 + d0 + c] = tile[c][r];
        }
    } else if (bid < 7168) {
        // cast Wo fp32 -> bf16 (4096 sub-blocks x 256 thr x float4)
        const size_t i = (size_t)(bid - 3072) * 256 + t;
        const float4 v = ((const float4*)Wo)[i];
        ushort4 o4;
        o4.x = f2bf(v.x); o4.y = f2bf(v.y); o4.z = f2bf(v.z); o4.w = f2bf(v.w);
        ((ushort4*)wo_b)[i] = o4;
    } else if (bid < 8192) {
        // layernorm: 4 rows/block, one per wave
        const size_t row = (size_t)(bid - 7168) * 4 + (t >> 6);
        const int l = t & 63;
        const float4 v = ((const float4*)(x + row * 256))[l];
        float s = v.x + v.y + v.z + v.w;
        float qq = v.x * v.x + v.y * v.y + v.z * v.z + v.w * v.w;
#pragma unroll
        for (int o = 32; o > 0; o >>= 1) {
            s += __shfl_xor(s, o, 64);
            qq += __shfl_xor(qq, o, 64);
        }
        const float mu = s * (1.0f / 256.0f);
        const float var = qq * (1.0f / 256.0f) - mu * mu;
        const float rs = rsqrtf(var + 1e-5f);
        const float4 gg = ((const float4*)g)[l];
        ushort4 o4;
        o4.x = f2bf((v.x - mu) * rs * (gg.x + 1.0f));
        o4.y = f2bf((v.y - mu) * rs * (gg.y + 1.0f));
        o4.z = f2bf((v.z - mu) * rs * (gg.z + 1.0f));
        o4.w = f2bf((v.w - mu) * rs * (gg.w + 1.0f));
        ((ushort4*)(xn + row * 256))[l] = o4;
    } else {
        // zero MtF/NbF (4 MB)
        const size_t i = (size_t)(bid - 8192) * 256 + t;
        ((float4*)MtF)[i] = float4{0.f, 0.f, 0.f, 0.f};
    }
}

// ---------------------------------------------------------------------------
// Flash-fused attention core (R14 verbatim).  512 blocks, 256 thr, 2 blocks/CU.
// Y  : [4096][2048]  row b*2048+i, col h*256+a  (SCALE folded) -> REGISTERS
// xn : [4096][256]           -> ldsB triple buffer (issue distance 2)
// Zt : [2][2048][2048]       -> ldsZ double buffer
// opart: [8][4096][256] fp32 per-head partials (plain stores, NO atomics);
//        per-head stride 1048576 floats (4 MB).
// XCD swizzle: blocks sharing (h,b) -> same XCD (wgid%8 round-robin assumption).
// ---------------------------------------------------------------------------
__global__ void __launch_bounds__(256, 2) attn_fused(
    const u16* __restrict__ Y, const u16* __restrict__ xn,
    const u16* __restrict__ Zt, float* __restrict__ opart)
{
    __shared__ u16 ldsB[3][128 * 32];  // 24 KB
    __shared__ u16 ldsZ[2][256 * 32];  // 32 KB (prologue: Y tile spans both)
    __shared__ u16 Pl[64 * 136];       // 17 KB
    __shared__ float l_lds[64];

    // bijective XCD swizzle: w = x + 32*y; xcd = w&7 gets hb in {2*xcd, 2*xcd+1}
    const int wgid = blockIdx.x + 32 * blockIdx.y;
    const int xcd = wgid & 7;
    const int p = wgid >> 3;           // 0..63
    const int hb = 2 * xcd + (p & 1);
    const int i0 = (p >> 1) * 64;
    const int h = hb >> 1, b = hb & 1;

    const int t = threadIdx.x;
    const int w = t >> 6, l = t & 63;
    const int wm = w >> 1, wn = w & 1;
    const int lr = l & 15, lk = l >> 4;
    const int sw = lk ^ ((lr >> 1) & 3);

    if (t < 64) l_lds[t] = 0.f;

    const u16* Yb = Y + (size_t)(b * 2048 + i0) * 2048 + h * 256;
    const u16* xb = xn + (size_t)b * 2048 * 256;
    const u16* Zb = Zt + (size_t)b * 4194304 + (size_t)h * 524288;

    // staging roles: xn (2 chunks/thread), Zt (4 chunks/thread)
    const int m0 = t >> 2, s0 = t & 3;
    const int c0 = s0 ^ ((m0 >> 1) & 3);
    const int m1 = 64 + m0;
    const int c1 = s0 ^ ((m1 >> 1) & 3);
    const int oB0 = (t & ~63) * 8;
    const int oB1 = (256 + (t & ~63)) * 8;

    const u16 *gZ0, *gZ1, *gZ2, *gZ3;
    const int oZ0 = (t & ~63) * 8;
    const int oZ1 = (256 + (t & ~63)) * 8;
    const int oZ2 = (512 + (t & ~63)) * 8;
    const int oZ3 = (768 + (t & ~63)) * 8;
    {
        const int q0 = t, q1 = 256 + t, q2 = 512 + t, q3 = 768 + t;
        const int mz0 = q0 >> 2, mz1 = q1 >> 2, mz2 = q2 >> 2, mz3 = q3 >> 2;
        const int cz0 = (q0 & 3) ^ ((mz0 >> 1) & 3);
        const int cz1 = (q1 & 3) ^ ((mz1 >> 1) & 3);
        const int cz2 = (q2 & 3) ^ ((mz2 >> 1) & 3);
        const int cz3 = (q3 & 3) ^ ((mz3 >> 1) & 3);
        gZ0 = Zb + (size_t)mz0 * 2048 + cz0 * 8;
        gZ1 = Zb + (size_t)mz1 * 2048 + cz1 * 8;
        gZ2 = Zb + (size_t)mz2 * 2048 + cz2 * 8;
        gZ3 = Zb + (size_t)mz3 * 2048 + cz3 * 8;
    }

    // ---- prologue: stage Y i-tile (64x256 = 32KB) into ldsZ, B(jt0,k0/k1) ----
    u16* ldsY = &ldsZ[0][0];
#pragma unroll
    for (int pp = 0; pp < 8; ++pp) {
        const int q = pp * 256 + t;
        const int kt = q >> 8, qq = q & 255;
        const int m = qq >> 2, s = qq & 3;
        const int c = s ^ ((m >> 1) & 3);
        GLDS16(Yb + (size_t)m * 2048 + kt * 32 + c * 8,
               &ldsY[(pp * 256 + (t & ~63)) * 8]);
    }
    GLDS16(xb + (size_t)m0 * 256 + c0 * 8, &ldsB[0][oB0]);        // B(0,0) -> slot 0
    GLDS16(xb + (size_t)m1 * 256 + c1 * 8, &ldsB[0][oB1]);
    GLDS16(xb + (size_t)m0 * 256 + 32 + c0 * 8, &ldsB[1][oB0]);   // B(0,1) -> slot 1
    GLDS16(xb + (size_t)m1 * 256 + 32 + c1 * 8, &ldsB[1][oB1]);
    vm_wait<4>();                      // Y done; [B(0,0), B(0,1)] in flight
    bar();

    // Y fragments -> registers (jt-invariant): 16x bf16x8 = 64 VGPR
    bf16x8 yr[8][2];
#pragma unroll
    for (int kt = 0; kt < 8; ++kt)
#pragma unroll
        for (int i = 0; i < 2; ++i)
            yr[kt][i] = *(const bf16x8*)&ldsY[kt * 2048 + (wm * 32 + i * 16 + lr) * 32 + sw * 8];

    f32x4 acc_o[2][8];
#pragma unroll
    for (int i = 0; i < 2; ++i)
#pragma unroll
        for (int j = 0; j < 8; ++j)
            acc_o[i][j] = f32x4{0.f, 0.f, 0.f, 0.f};
    float lsum[8];
#pragma unroll
    for (int i = 0; i < 8; ++i) lsum[i] = 0.f;

// phase: wait (counted); barrier; issue; compute kt from ldsB[kt%3]
#define S_STEP(KT, VMC, ISSUE)                                                        \
    {                                                                                 \
        vm_wait<VMC>(); bar();                                                        \
        ISSUE;                                                                        \
        bf16x8 bv[4];                                                                 \
        _Pragma("unroll")                                                             \
        for (int j = 0; j < 4; ++j)                                                   \
            bv[j] = *(const bf16x8*)&ldsB[(KT) % 3][(wn * 64 + j * 16 + lr) * 32 + sw * 8]; \
        __builtin_amdgcn_s_setprio(1);                                                \
        _Pragma("unroll")                                                             \
        for (int j = 0; j < 4; ++j) {                                                 \
            acc_s[0][j] = __builtin_amdgcn_mfma_f32_16x16x32_bf16(yr[KT][0], bv[j], acc_s[0][j], 0, 0, 0); \
            acc_s[1][j] = __builtin_amdgcn_mfma_f32_16x16x32_bf16(yr[KT][1], bv[j], acc_s[1][j], 0, 0, 0); \
        }                                                                             \
        __builtin_amdgcn_s_setprio(0);                                                \
    }

#define PV_STEP(KT, VMC, ISSUE)                                                       \
    {                                                                                 \
        vm_wait<VMC>(); bar();                                                        \
        ISSUE;                                                                        \
        bf16x8 av[2];                                                                 \
        av[0] = *(const bf16x8*)&Pl[(wm * 32 + lr) * 136 + (KT) * 32 + lk * 8];       \
        av[1] = *(const bf16x8*)&Pl[(wm * 32 + 16 + lr) * 136 + (KT) * 32 + lk * 8];  \
        __builtin_amdgcn_s_setprio(1);                                                \
        _Pragma("unroll")                                                             \
        for (int jf = 0; jf < 8; ++jf) {                                              \
            const bf16x8 bz = *(const bf16x8*)&ldsZ[(KT) & 1][(wn * 128 + jf * 16 + lr) * 32 + sw * 8]; \
            acc_o[0][jf] = __builtin_amdgcn_mfma_f32_16x16x32_bf16(av[0], bz, acc_o[0][jf], 0, 0, 0);   \
            acc_o[1][jf] = __builtin_amdgcn_mfma_f32_16x16x32_bf16(av[1], bz, acc_o[1][jf], 0, 0, 0);   \
        }                                                                             \
        __builtin_amdgcn_s_setprio(0);                                                \
    }

#define ISSUE_B(JBASE, KK, SLOT)                                                      \
    GLDS16(JBASE + (size_t)m0 * 256 + (KK) * 32 + c0 * 8, &ldsB[SLOT][oB0]);          \
    GLDS16(JBASE + (size_t)m1 * 256 + (KK) * 32 + c1 * 8, &ldsB[SLOT][oB1])

#define ISSUE_Z(OFF, ZBUF)                                                            \
    GLDS16(gZ0 + (OFF), &ldsZ[ZBUF][oZ0]);                                            \
    GLDS16(gZ1 + (OFF), &ldsZ[ZBUF][oZ1]);                                            \
    GLDS16(gZ2 + (OFF), &ldsZ[ZBUF][oZ2]);                                            \
    GLDS16(gZ3 + (OFF), &ldsZ[ZBUF][oZ3])

    for (int jt = 0; jt < 16; ++jt) {
        const int j0 = jt * 128;
        const int jn = ((jt + 1) & 15) * 128;   // jt=15 wraps: harmless dummy prefetch
        const u16* xbj = xb + (size_t)j0 * 256;
        const u16* xbn = xb + (size_t)jn * 256;

        f32x4 acc_s[2][4];
#pragma unroll
        for (int i = 0; i < 2; ++i)
#pragma unroll
            for (int j = 0; j < 4; ++j)
                acc_s[i][j] = f32x4{0.f, 0.f, 0.f, 0.f};

        // queues (per wave, in-order): entering S0: [B0(2), B1(2)]
        S_STEP(0, 2, ISSUE_B(xbj, 2, 2))   // retire B0; [B1,B2]
        S_STEP(1, 2, ISSUE_B(xbj, 3, 0))   // [B2,B3]
        S_STEP(2, 2, ISSUE_B(xbj, 4, 1))
        S_STEP(3, 2, ISSUE_B(xbj, 5, 2))
        S_STEP(4, 2, ISSUE_B(xbj, 6, 0))
        S_STEP(5, 2, ISSUE_B(xbj, 7, 1))
        S_STEP(6, 2, ISSUE_Z(j0, 0))       // [B7,Z0]
        S_STEP(7, 4, ISSUE_Z(j0 + 32, 1))  // [Z0,Z1]

        // ---- exp + l partials + P -> LDS (C-layout -> [row][col]) ----
#pragma unroll
        for (int i = 0; i < 2; ++i)
#pragma unroll
            for (int j = 0; j < 4; ++j)
#pragma unroll
                for (int r = 0; r < 4; ++r) {
                    const float e = __expf(acc_s[i][j][r]);
                    lsum[i * 4 + r] += e;
                    Pl[(wm * 32 + i * 16 + lk * 4 + r) * 136 + wn * 64 + j * 16 + lr] = f2bf(e);
                }
        lgk0();                            // Pl writes done; barrier comes in PV0

        // PV queues: entering PV0: [Z0(4), Z1(4)]
        PV_STEP(0, 4, ((void)0))           // retire Z0; [Z1]
        PV_STEP(1, 0, ISSUE_Z(j0 + 64, 0)) // retire Z1; issue Z2; [Z2]
        PV_STEP(2, 0, ISSUE_Z(j0 + 96, 1); ISSUE_B(xbn, 0, 0))  // [Z3,B0']
        PV_STEP(3, 2, ISSUE_B(xbn, 1, 1))  // retire Z3; [B0',B1']
    }

    // ---- finalize l: butterfly over lr lanes, cross-wave LDS atomic ----
#pragma unroll
    for (int i = 0; i < 2; ++i)
#pragma unroll
        for (int r = 0; r < 4; ++r) {
            float s = lsum[i * 4 + r];
            s += __shfl_xor(s, 1, 64);
            s += __shfl_xor(s, 2, 64);
            s += __shfl_xor(s, 4, 64);
            s += __shfl_xor(s, 8, 64);
            if (lr == 0) atomicAdd(&l_lds[wm * 32 + i * 16 + lk * 4 + r], s);
        }
    __syncthreads();

    // ---- scale by 1/l, plain-store per-head partial (NO global atomics) ----
    float* oh = opart + (size_t)h * 1048576;   // 4096*256 floats per head
#pragma unroll
    for (int i = 0; i < 2; ++i)
#pragma unroll
        for (int r = 0; r < 4; ++r) {
            const int row = wm * 32 + i * 16 + lk * 4 + r;
            const float rl = 1.0f / l_lds[row];
            float* orow = oh + (size_t)(b * 2048 + i0 + row) * 256 + wn * 128;
#pragma unroll
            for (int jf = 0; jf < 8; ++jf)
                orow[jf * 16 + lr] = acc_o[i][jf][r] * rl;
        }
}

// ---------------------------------------------------------------------------
// Head reduction: out[i] = sum_h opart[h][i], i over 4096*256 fp32.
// ---------------------------------------------------------------------------
__global__ void __launch_bounds__(256) hreduce_kernel(const float* __restrict__ opart,
                                                      float* __restrict__ out)
{
    const size_t i = (size_t)blockIdx.x * 256 + threadIdx.x;   // float4 index
    float4 s = ((const float4*)opart)[i];
#pragma unroll
    for (int h = 1; h < 8; ++h) {
        const float4 v = ((const float4*)(opart + (size_t)h * 1048576))[i];
        s.x += v.x; s.y += v.y; s.z += v.z; s.w += v.w;
    }
    ((float4*)out)[i] = s;
}

__global__ void __launch_bounds__(256) cast_bf16_kernel(const float* __restrict__ src,
                                                        u16* __restrict__ dst, float scale)
{
    const size_t i = (size_t)blockIdx.x * 256 + threadIdx.x;
    const float4 v = ((const float4*)src)[i];
    ushort4 o4;
    o4.x = f2bf(v.x * scale);
    o4.y = f2bf(v.y * scale);
    o4.z = f2bf(v.z * scale);
    o4.w = f2bf(v.w * scale);
    ((ushort4*)dst)[i] = o4;
}

extern "C" void kernel_launch(void* const* d_in, const int* in_sizes, int n_in,
                              void* d_out, int out_size, void* d_ws, size_t ws_size,
                              hipStream_t stream)
{
    (void)in_sizes; (void)n_in; (void)ws_size; (void)out_size;
    const float* x     = (const float*)d_in[0];
    const float* gamma = (const float*)d_in[1];
    const float* Wq    = (const float*)d_in[2];
    const float* Wk    = (const float*)d_in[3];
    const float* Wv    = (const float*)d_in[4];
    const float* Wo    = (const float*)d_in[5];
    float* out = (float*)d_out;

    char* ws = (char*)d_ws;
    const size_t MB = 1048576;
    u16* wqt   = (u16*)(ws);             // [3][8][256][2048] bf16 (SCALE folded in Wq)
    u16* wkt   = (u16*)(ws + 8 * MB);
    u16* wvt   = (u16*)(ws + 16 * MB);
    u16* wo    = (u16*)(ws + 24 * MB);   // [256][16384] bf16
    u16* xn    = (u16*)(ws + 32 * MB);   // [4096][256] bf16
    u16* Mt    = (u16*)(ws + 34 * MB);   // [8*256][256] bf16 (Mt_h = M_h^T)
    float* MtF = (float*)(ws + 36 * MB); // fp32 split-K accum: Mt (2 MB) + Nb (2 MB)
    u16* Nb    = (u16*)(ws + 35 * MB);   // [8*256][256] bf16 (contiguous after Mt)
    u16* Y     = (u16*)(ws + 44 * MB);   // [4096][2048] bf16
    u16* Zt    = (u16*)(ws + 60 * MB);   // [2][2048][2048] bf16
    float* opart = (float*)(ws);         // [8][4096][256] fp32 (stride 1048576
                                         // floats/head, 32 MB) -- reuses dead
                                         // weight-staging region 0..32MB.

    // 1. fused prologue: tcast3 + cast_wo + ln + zero(MtF)
    prep_kernel<<<9216, 256, 0, stream>>>(x, gamma, Wq, Wk, Wv, Wo, wqt, wo, xn, MtF);

    // 2. both weight GEMMs (split-K x4, fp32 atomics): Mt_h = wkt_h.wqt_h^T,
    //    Nb_h = Wo_h.wvt_h^T
    gemm_w<<<dim3(2, 2, 64), 256, 0, stream>>>(wkt, wqt, wo, wvt, MtF);

    // 3. cast MtF+NbF (4 MB contiguous) -> Mt+Nb (2 MB contiguous)
    cast_bf16_kernel<<<1024, 256, 0, stream>>>(MtF, Mt, 1.0f);

    // 4. Y = xn.Mt^T (2 row-halves) and Zt = Nb.xn^T (2 batches), one dispatch
    gemm_yz<<<dim3(16, 16, 4), 256, 0, stream>>>(xn, Mt, Nb, Y, Zt);

    // 5. fused S -> softmax -> PV -> per-head partial stores
    attn_fused<<<dim3(32, 16), 256, 0, stream>>>(Y, xn, Zt, opart);

    // 6. head-sum reduction: out = sum_h opart[h]
    hreduce_kernel<<<1024, 256, 0, stream>>>(opart, out);
}